// Round 4
// baseline (41598.199 us; speedup 1.0000x reference)
//
#include <hip/hip_runtime.h>
#include <stdint.h>

// SlidingBaseFc on MI355X (gfx950).
// Persistent cooperative kernel: 8 row-groups (128 batch rows each) x 32 WGs x 256 thr.
// Each group runs the 84-step recurrence independently; intra-group atomic-counter
// barriers between layer phases (one global barrier after weight prep).
// Numerics: split-bf16 (hi+lo) 4-pass MFMA (product err ~2^-27), fp32 accumulate,
// fp32 bias/relu epilogue. All activation buffers are PER-GROUP PRIVATE slices
// (round-3 bug: absolute-row indexing with phase-dependent strides aliased across
// unsynchronized groups -> absmax 3.0).

#define NTHR 256
#define NG 8
#define WPG 32
#define LDSTR 40            // LDS row stride in u16 for 32-wide K tiles
#define BATCH 1024
#define TSEQ 85
#define FEAT 36
#define SRCROW (TSEQ * FEAT)   // 3060
#define NCLS 69
#define GROWS 128           // rows per group

typedef short s8b __attribute__((ext_vector_type(8)));
typedef float f32x4 __attribute__((ext_vector_type(4)));
typedef int i32x4 __attribute__((ext_vector_type(4)));

union V8 { s8b v; uint16_t u[8]; i32x4 q; };

__device__ __forceinline__ uint16_t f2bf(float f) {
  uint32_t u = __float_as_uint(f);
  u += 0x7FFFu + ((u >> 16) & 1u);   // RNE to bf16
  return (uint16_t)(u >> 16);
}
__device__ __forceinline__ float bf2f(uint16_t h) {
  return __uint_as_float(((uint32_t)h) << 16);
}
__device__ __forceinline__ void split_bf(float x, uint16_t &ms, uint16_t &ls) {
  ms = f2bf(x);
  ls = f2bf(x - bf2f(ms));   // residual; subtraction exact in fp32
}

// Barrier: monotonic counter, agent-scope fences; watchdog caps a deadlock at
// ~20 ms per barrier (wrong answer beats a hung container).
__device__ __forceinline__ void ctr_barrier(unsigned *ctr, unsigned target) {
  __threadfence();
  __syncthreads();
  if (threadIdx.x == 0) {
    __hip_atomic_fetch_add(ctr, 1u, __ATOMIC_RELAXED, __HIP_MEMORY_SCOPE_AGENT);
    const long long t0 = wall_clock64();
    while (__hip_atomic_load(ctr, __ATOMIC_RELAXED, __HIP_MEMORY_SCOPE_AGENT) < target) {
      __builtin_amdgcn_s_sleep(8);
      if (wall_clock64() - t0 > 2000000LL) break;   // ~20 ms @ 100 MHz
    }
  }
  __syncthreads();
  __threadfence();
}

// One GEMM phase for this group's 128 rows: out = act @ W + bias (optional relu).
// ALL row indices are GROUP-LOCAL (0..127); activation/output pointers are
// pre-offset per group by the caller. MI/NI: 16x16 fragment repeats per wave
// (wave tile 16*MI x 16*NI, 2x2 waves). AFP32: A is fp32, split on the fly,
// K-predicated. EPI=0: write split-bf16 planes. EPI=1: final layer (N padded
// to 128, cols<69): fp32 stores to fres (+finit) and split into hms/hls
// (carried-state planes) at cols 72..140.
template <int MI, int NI, bool AFP32, int EPI>
__device__ void gemm_phase(int wg,
    const uint16_t *__restrict__ Ams, const uint16_t *__restrict__ Als,
    const float *__restrict__ Afp, int lda, int Kpad, int Kreal,
    const float *__restrict__ W, int ldw, int N,
    const float *__restrict__ bias, int relu,
    uint16_t *__restrict__ Oms, uint16_t *__restrict__ Ols, int ldo,
    uint16_t *sAms, uint16_t *sAls, uint16_t *sBms, uint16_t *sBls,
    float *__restrict__ fres, float *__restrict__ finit,
    uint16_t *__restrict__ hms, uint16_t *__restrict__ hls)
{
  constexpr int TM = 32 * MI, TN = 32 * NI;
  const int nbs = N / TN;
  const int active = (GROWS / TM) * nbs;
  if (wg >= active) return;          // whole block exits; barriers are in caller
  const int mb = wg / nbs, nb = wg - mb * nbs;
  const int m_base = mb * TM;        // group-local
  const int n0 = nb * TN;
  const int tid = threadIdx.x;
  const int lane = tid & 63;
  const int wid = tid >> 6;
  const int wr = wid >> 1, wc = wid & 1;
  const int r16 = lane & 15, kg = lane >> 4;

  const f32x4 zero = {0.f, 0.f, 0.f, 0.f};
  f32x4 acc[MI][NI];
#pragma unroll
  for (int i = 0; i < MI; ++i)
#pragma unroll
    for (int j = 0; j < NI; ++j) acc[i][j] = zero;

  for (int k0 = 0; k0 < Kpad; k0 += 32) {
    __syncthreads();
    // ---- stage A tile (TM x 32) into ms/ls planes ----
    if (!AFP32) {
      for (int c = tid; c < TM * 4; c += NTHR) {
        const int m = c >> 2, ko = (c & 3) * 8;
        const size_t go = (size_t)(m_base + m) * lda + k0 + ko;
        *(i32x4 *)&sAms[m * LDSTR + ko] = *(const i32x4 *)(Ams + go);
        *(i32x4 *)&sAls[m * LDSTR + ko] = *(const i32x4 *)(Als + go);
      }
    } else {
      for (int c = tid; c < TM * 4; c += NTHR) {
        const int m = c >> 2, ko = (c & 3) * 8;
        const float *sp = Afp + (size_t)(m_base + m) * lda + k0 + ko;
        V8 vm, vl;
#pragma unroll
        for (int j = 0; j < 8; ++j) {
          const float x = (k0 + ko + j < Kreal) ? sp[j] : 0.f;
          split_bf(x, vm.u[j], vl.u[j]);
        }
        *(i32x4 *)&sAms[m * LDSTR + ko] = vm.q;
        *(i32x4 *)&sAls[m * LDSTR + ko] = vl.q;
      }
    }
    // ---- stage B tile transposed (TN x 32), fp32 -> split on the fly ----
    {
      constexpr int KP = TN / 8;       // k's per thread: 8 (TN=64) or 16 (TN=128)
      const int n = tid % TN, kq = tid / TN;
      uint16_t mv[KP], lv[KP];
#pragma unroll
      for (int i = 0; i < KP; ++i) {
        const int kk = k0 + kq * KP + i;
        const float x = (kk < Kreal) ? W[(size_t)kk * ldw + n0 + n] : 0.f;
        split_bf(x, mv[i], lv[i]);
      }
#pragma unroll
      for (int c = 0; c < KP / 8; ++c) {
        V8 vm, vl;
#pragma unroll
        for (int j = 0; j < 8; ++j) { vm.u[j] = mv[c * 8 + j]; vl.u[j] = lv[c * 8 + j]; }
        *(i32x4 *)&sBms[n * LDSTR + kq * KP + c * 8] = vm.q;
        *(i32x4 *)&sBls[n * LDSTR + kq * KP + c * 8] = vl.q;
      }
    }
    __syncthreads();
    // ---- fragments + 4-pass MFMA (mm, ml, lm, ll) ----
    s8b fam[MI], fal[MI], fbm[NI], fbl[NI];
#pragma unroll
    for (int i = 0; i < MI; ++i) {
      const int ro = (wr * (16 * MI) + i * 16 + r16) * LDSTR + kg * 8;
      fam[i] = *(const s8b *)&sAms[ro];
      fal[i] = *(const s8b *)&sAls[ro];
    }
#pragma unroll
    for (int j = 0; j < NI; ++j) {
      const int co = (wc * (16 * NI) + j * 16 + r16) * LDSTR + kg * 8;
      fbm[j] = *(const s8b *)&sBms[co];
      fbl[j] = *(const s8b *)&sBls[co];
    }
#pragma unroll
    for (int i = 0; i < MI; ++i)
#pragma unroll
      for (int j = 0; j < NI; ++j) {
        acc[i][j] = __builtin_amdgcn_mfma_f32_16x16x32_bf16(fam[i], fbm[j], acc[i][j], 0, 0, 0);
        acc[i][j] = __builtin_amdgcn_mfma_f32_16x16x32_bf16(fam[i], fbl[j], acc[i][j], 0, 0, 0);
        acc[i][j] = __builtin_amdgcn_mfma_f32_16x16x32_bf16(fal[i], fbm[j], acc[i][j], 0, 0, 0);
        acc[i][j] = __builtin_amdgcn_mfma_f32_16x16x32_bf16(fal[i], fbl[j], acc[i][j], 0, 0, 0);
      }
  }
  // ---- epilogue (C/D: col = lane&15, row = (lane>>4)*4 + reg) ----
#pragma unroll
  for (int i = 0; i < MI; ++i)
#pragma unroll
    for (int j = 0; j < NI; ++j) {
      const int row0 = m_base + wr * (16 * MI) + i * 16 + kg * 4;   // group-local
      const int col = n0 + wc * (16 * NI) + j * 16 + r16;
      if (EPI == 0) {
        const float bv = bias[col];
#pragma unroll
        for (int r = 0; r < 4; ++r) {
          float v = acc[i][j][r] + bv;
          if (relu) v = fmaxf(v, 0.f);
          uint16_t ms, ls; split_bf(v, ms, ls);
          const size_t o = (size_t)(row0 + r) * ldo + col;
          Oms[o] = ms; Ols[o] = ls;
        }
      } else {
        if (col < NCLS) {
          const float bv = bias[col];
#pragma unroll
          for (int r = 0; r < 4; ++r) {
            const float v = acc[i][j][r] + bv;
            fres[(size_t)(row0 + r) * (TSEQ * NCLS) + col] = v;
            if (finit) finit[(size_t)(row0 + r) * NCLS + col] = v;
            uint16_t ms, ls; split_bf(v, ms, ls);
            const size_t ho = (size_t)(row0 + r) * 160 + 72 + col;
            hms[ho] = ms; hls[ho] = ls;
          }
        }
      }
    }
}

// Helper WGs (2..17) fill l1 cols 0..71 (source features) for step next_t.
// l1 pointers are per-group slices; rows group-local.
__device__ __forceinline__ void stage_l1_src(int wg, const float *__restrict__ src_g,
                                             uint16_t *__restrict__ l1ms,
                                             uint16_t *__restrict__ l1ls, int next_t) {
  if (wg < 2 || wg >= 18 || next_t >= TSEQ) return;
  const int mrow = (wg - 2) * 8;     // group-local
  for (int e = threadIdx.x; e < 8 * 72; e += NTHR) {
    const int m = e / 72, c = e - (e / 72) * 72;
    const float x = src_g[(size_t)(mrow + m) * SRCROW + (size_t)(next_t - 1) * FEAT + c];
    uint16_t ms, ls; split_bf(x, ms, ls);
    const size_t o = (size_t)(mrow + m) * 160 + c;
    l1ms[o] = ms; l1ls[o] = ls;
  }
}

// ---- workspace layout (per-group-private activation slices; ~17.1 MiB) ----
#define SZ_ACT ((size_t)BATCH * 2048 * 2)      // one u16 plane, all groups
#define GSLICE ((size_t)GROWS * 2048)          // per-group slice, u16 elements
#define OFF_A0MS ((size_t)4096)
#define OFF_A0LS (OFF_A0MS + SZ_ACT)
#define OFF_A1MS (OFF_A0LS + SZ_ACT)
#define OFF_A1LS (OFF_A1MS + SZ_ACT)
#define SZ_L1 ((size_t)BATCH * 160 * 2)
#define GSL1 ((size_t)GROWS * 160)             // per-group l1 slice, u16 elements
#define OFF_L1MS (OFF_A1LS + SZ_ACT)
#define OFF_L1LS (OFF_L1MS + SZ_L1)
#define SZ_WP ((size_t)512 * 128 * 4)
#define OFF_WI3 (OFF_L1LS + SZ_L1)
#define OFF_W44 (OFF_WI3 + SZ_WP)
#define OFF_B44 (OFF_W44 + SZ_WP)
#define WS_NEEDED (OFF_B44 + 512)

extern "C" __global__ void __launch_bounds__(NTHR, 1)
sbfc_kernel(const float *__restrict__ src,
            const float *__restrict__ wi1, const float *__restrict__ bi1,
            const float *__restrict__ wi2, const float *__restrict__ bi2,
            const float *__restrict__ wi25, const float *__restrict__ bi25,
            const float *__restrict__ wi3, const float *__restrict__ bi3,
            const float *__restrict__ w1, const float *__restrict__ b1,
            const float *__restrict__ w12, const float *__restrict__ b12,
            const float *__restrict__ w2, const float *__restrict__ b2,
            const float *__restrict__ w22, const float *__restrict__ b22,
            const float *__restrict__ w3, const float *__restrict__ b3,
            const float *__restrict__ w4, const float *__restrict__ b4,
            const float *__restrict__ w4d, const float *__restrict__ b4d,
            float *__restrict__ out, char *ws)
{
  __shared__ uint16_t sAms[128 * LDSTR], sAls[128 * LDSTR];
  __shared__ uint16_t sBms[128 * LDSTR], sBls[128 * LDSTR];

  const int bid = blockIdx.x;
  const int g = bid & (NG - 1);   // XCD-affinity heuristic (perf-only)
  const int wg = bid >> 3;        // 0..31 within group
  const int tid = threadIdx.x;

  unsigned *ctr = (unsigned *)ws + g * 16;       // per-group counters, 64B apart
  unsigned *ctrg = (unsigned *)(ws + 2048);      // global prep counter

  // Per-group private slices (group-local row addressing everywhere below).
  uint16_t *a0ms = (uint16_t *)(ws + OFF_A0MS) + g * GSLICE;
  uint16_t *a0ls = (uint16_t *)(ws + OFF_A0LS) + g * GSLICE;
  uint16_t *a1ms = (uint16_t *)(ws + OFF_A1MS) + g * GSLICE;
  uint16_t *a1ls = (uint16_t *)(ws + OFF_A1LS) + g * GSLICE;
  uint16_t *l1ms = (uint16_t *)(ws + OFF_L1MS) + g * GSL1;
  uint16_t *l1ls = (uint16_t *)(ws + OFF_L1LS) + g * GSL1;
  float *wi3p = (float *)(ws + OFF_WI3);
  float *w44 = (float *)(ws + OFF_W44);
  float *b44 = (float *)(ws + OFF_B44);

  const float *src_g = src + (size_t)g * GROWS * SRCROW;
  float *out_g = out + (size_t)g * GROWS * TSEQ * NCLS;
  float *finit_g = out + (size_t)BATCH * TSEQ * NCLS + (size_t)g * GROWS * NCLS;

  // ---- prep (single copies of fused weights, designated blocks) ----
  if (bid < 16) {                    // w44 = w4 @ w4d, N-padded to 128 with zeros
    const int kb = bid * 32;
    for (int e = tid; e < 32 * 128; e += NTHR) {
      const int k = kb + (e >> 7), n = e & 127;
      float s = 0.f;
      if (n < NCLS) {
        const float *w4r = w4 + (size_t)k * 512;
        for (int j = 0; j < 512; ++j) s = fmaf(w4r[j], w4d[(size_t)j * NCLS + n], s);
      }
      w44[(size_t)k * 128 + n] = s;
    }
  } else if (bid < 24) {             // wi3 padded to [512][128]
    const int kb = (bid - 16) * 64;
    for (int e = tid; e < 64 * 128; e += NTHR) {
      const int k = kb + (e >> 7), n = e & 127;
      wi3p[(size_t)k * 128 + n] = (n < NCLS) ? wi3[(size_t)k * NCLS + n] : 0.f;
    }
  } else if (bid == 24) {            // b44 = b4 @ w4d + b4d (padded)
    for (int n = tid; n < 128; n += NTHR) {
      float s = 0.f;
      if (n < NCLS) {
        s = b4d[n];
        for (int j = 0; j < 512; ++j) s = fmaf(b4[j], w4d[(size_t)j * NCLS + n], s);
      }
      b44[n] = s;
    }
  } else if (bid < 29) {             // zero l1 pad cols 141..159, all 1024 rows
    uint16_t *l1m0 = (uint16_t *)(ws + OFF_L1MS);
    uint16_t *l1l0 = (uint16_t *)(ws + OFF_L1LS);
    const int part = bid - 25;       // 0..3 -> abs rows part*256..+255
    for (int e = tid; e < 256 * 19; e += NTHR) {
      const int m = part * 256 + e / 19, c = 141 + (e - (e / 19) * 19);
      const size_t o = (size_t)(m >> 7) * GSL1 + (size_t)(m & 127) * 160 + c;
      l1m0[o] = 0; l1l0[o] = 0;
    }
  }
  ctr_barrier(ctrg, 256);            // one global barrier publishes prep

  unsigned ph = 0;

  // ---- init MLP: I1(relu) -> I2(relu) -> I25(lin) -> I3(lin, final-style) ----
  gemm_phase<4, 2, true, 0>(wg, nullptr, nullptr, src_g, SRCROW, 3072, SRCROW,
                            wi1, 2048, 2048, bi1, 1, a0ms, a0ls, 2048,
                            sAms, sAls, sBms, sBls, nullptr, nullptr, nullptr, nullptr);
  ++ph; ctr_barrier(ctr, ph * WPG);
  gemm_phase<2, 2, false, 0>(wg, a0ms, a0ls, nullptr, 2048, 2048, 2048,
                             wi2, 1024, 1024, bi2, 1, a1ms, a1ls, 1024,
                             sAms, sAls, sBms, sBls, nullptr, nullptr, nullptr, nullptr);
  ++ph; ctr_barrier(ctr, ph * WPG);
  gemm_phase<2, 2, false, 0>(wg, a1ms, a1ls, nullptr, 1024, 1024, 1024,
                             wi25, 512, 512, bi25, 0, a0ms, a0ls, 512,
                             sAms, sAls, sBms, sBls, nullptr, nullptr, nullptr, nullptr);
  ++ph; ctr_barrier(ctr, ph * WPG);
  gemm_phase<2, 4, false, 1>(wg, a0ms, a0ls, nullptr, 512, 512, 512,
                             wi3p, 128, 128, bi3, 0, nullptr, nullptr, 0,
                             sAms, sAls, sBms, sBls, out_g, finit_g, l1ms, l1ls);
  stage_l1_src(wg, src_g, l1ms, l1ls, 1);
  ++ph; ctr_barrier(ctr, ph * WPG);

  // ---- 84 sequential steps ----
  for (int t = 1; t < TSEQ; ++t) {
    gemm_phase<4, 2, false, 0>(wg, l1ms, l1ls, nullptr, 160, 160, 141,
                               w1, 2048, 2048, b1, 1, a0ms, a0ls, 2048,
                               sAms, sAls, sBms, sBls, nullptr, nullptr, nullptr, nullptr);
    ++ph; ctr_barrier(ctr, ph * WPG);
    gemm_phase<4, 2, false, 0>(wg, a0ms, a0ls, nullptr, 2048, 2048, 2048,
                               w12, 2048, 2048, b12, 1, a1ms, a1ls, 2048,
                               sAms, sAls, sBms, sBls, nullptr, nullptr, nullptr, nullptr);
    ++ph; ctr_barrier(ctr, ph * WPG);
    gemm_phase<2, 2, false, 0>(wg, a1ms, a1ls, nullptr, 2048, 2048, 2048,
                               w2, 1024, 1024, b2, 1, a0ms, a0ls, 1024,
                               sAms, sAls, sBms, sBls, nullptr, nullptr, nullptr, nullptr);
    ++ph; ctr_barrier(ctr, ph * WPG);
    gemm_phase<2, 2, false, 0>(wg, a0ms, a0ls, nullptr, 1024, 1024, 1024,
                               w22, 1024, 1024, b22, 1, a1ms, a1ls, 1024,
                               sAms, sAls, sBms, sBls, nullptr, nullptr, nullptr, nullptr);
    ++ph; ctr_barrier(ctr, ph * WPG);
    gemm_phase<2, 2, false, 0>(wg, a1ms, a1ls, nullptr, 1024, 1024, 1024,
                               w3, 512, 512, b3, 1, a0ms, a0ls, 512,
                               sAms, sAls, sBms, sBls, nullptr, nullptr, nullptr, nullptr);
    ++ph; ctr_barrier(ctr, ph * WPG);
    gemm_phase<2, 4, false, 1>(wg, a0ms, a0ls, nullptr, 512, 512, 512,
                               w44, 128, 128, b44, 0, nullptr, nullptr, 0,
                               sAms, sAls, sBms, sBls,
                               out_g + (size_t)t * NCLS, nullptr, l1ms, l1ls);
    stage_l1_src(wg, src_g, l1ms, l1ls, t + 1);
    ++ph; ctr_barrier(ctr, ph * WPG);
  }
}

extern "C" void kernel_launch(void *const *d_in, const int *in_sizes, int n_in,
                              void *d_out, int out_size, void *d_ws, size_t ws_size,
                              hipStream_t stream) {
  if (ws_size < WS_NEEDED) return;   // clean mismatch beats an OOB-write crash

  const float *src = (const float *)d_in[0];
  const float *wi1 = (const float *)d_in[1];
  const float *bi1 = (const float *)d_in[2];
  const float *wi2 = (const float *)d_in[3];
  const float *bi2 = (const float *)d_in[4];
  const float *wi25 = (const float *)d_in[5];
  const float *bi25 = (const float *)d_in[6];
  const float *wi3 = (const float *)d_in[7];
  const float *bi3 = (const float *)d_in[8];
  const float *w1 = (const float *)d_in[9];
  const float *b1 = (const float *)d_in[10];
  const float *w12 = (const float *)d_in[11];
  const float *b12 = (const float *)d_in[12];
  const float *w2 = (const float *)d_in[13];
  const float *b2 = (const float *)d_in[14];
  const float *w22 = (const float *)d_in[15];
  const float *b22 = (const float *)d_in[16];
  const float *w3 = (const float *)d_in[17];
  const float *b3 = (const float *)d_in[18];
  const float *w4 = (const float *)d_in[19];
  const float *b4 = (const float *)d_in[20];
  const float *w4d = (const float *)d_in[21];
  const float *b4d = (const float *)d_in[22];
  float *out = (float *)d_out;
  char *ws = (char *)d_ws;

  // Zero the barrier counters (d_ws is poisoned 0xAA before every launch).
  hipMemsetAsync(d_ws, 0, 4096, stream);

  void *args[] = {&src, &wi1, &bi1, &wi2, &bi2, &wi25, &bi25, &wi3, &bi3,
                  &w1, &b1, &w12, &b12, &w2, &b2, &w22, &b22, &w3, &b3,
                  &w4, &b4, &w4d, &b4d, &out, &ws};

  int coop = 0;
  hipDeviceGetAttribute(&coop, hipDeviceAttributeCooperativeLaunch, 0);
  hipError_t rc = hipErrorUnknown;
  if (coop) {
    rc = hipLaunchCooperativeKernel((const void *)sbfc_kernel, dim3(NG * WPG),
                                    dim3(NTHR), args, 0, stream);
  }
  if (rc != hipSuccess) {
    // Fallback: plain launch. 256 blocks @ 1 block/CU on an idle 256-CU chip
    // co-schedule in practice; the watchdog bounds the damage if not.
    hipLaunchKernelGGL(sbfc_kernel, dim3(NG * WPG), dim3(NTHR), 0, stream,
                       src, wi1, bi1, wi2, bi2, wi25, bi25, wi3, bi3,
                       w1, b1, w12, b12, w2, b2, w22, b22, w3, b3, w4, b4, w4d, b4d,
                       out, ws);
  }
}

// Round 7
// 32485.809 us; speedup vs baseline: 1.2805x; 1.2805x over previous
//
#include <hip/hip_runtime.h>
#include <stdint.h>

// SlidingBaseFc on MI355X (gfx950).
// Persistent cooperative kernel: 8 row-groups (128 rows) x 32 WGs x 256 thr.
// Round-5 changes vs round-4 (which passed, 41.6 ms, MfmaUtil 5.5% = latency-bound):
//  * Recurrent weights pre-split ONCE into bf16 hi/lo planes [N][Kpad] in ws
//    (B staging becomes vectorized i32x4 copies; no per-iter fp32 scalar loads/splits).
//  * Reg-staged double-buffered LDS pipeline: prefetch tile k+1 into registers
//    during MFMA of tile k; ONE __syncthreads per k-iter (was 2).
//  * Runtime fallback (ps=0) if ws_size < ~51 MB: fp32 on-the-fly B, still pipelined.

#define NTHR 256
#define NG 8
#define WPG 32
#define LDSTR 40            // LDS row stride in u16 (80 B, 16B-aligned, 2-way banks max on frag reads)
#define BATCH 1024
#define TSEQ 85
#define FEAT 36
#define SRCROW (TSEQ * FEAT)   // 3060
#define NCLS 69
#define GROWS 128

typedef short s8b __attribute__((ext_vector_type(8)));
typedef float f32x4 __attribute__((ext_vector_type(4)));
typedef int i32x4 __attribute__((ext_vector_type(4)));

union V8 { s8b v; uint16_t u[8]; i32x4 q; };

__device__ __forceinline__ uint16_t f2bf(float f) {
  uint32_t u = __float_as_uint(f);
  u += 0x7FFFu + ((u >> 16) & 1u);   // RNE
  return (uint16_t)(u >> 16);
}
__device__ __forceinline__ float bf2f(uint16_t h) {
  return __uint_as_float(((uint32_t)h) << 16);
}
__device__ __forceinline__ void split_bf(float x, uint16_t &ms, uint16_t &ls) {
  ms = f2bf(x);
  ls = f2bf(x - bf2f(ms));   // residual; subtraction exact in fp32
}

__device__ __forceinline__ void ctr_barrier(unsigned *ctr, unsigned target) {
  __threadfence();
  __syncthreads();
  if (threadIdx.x == 0) {
    __hip_atomic_fetch_add(ctr, 1u, __ATOMIC_RELAXED, __HIP_MEMORY_SCOPE_AGENT);
    const long long t0 = wall_clock64();
    while (__hip_atomic_load(ctr, __ATOMIC_RELAXED, __HIP_MEMORY_SCOPE_AGENT) < target) {
      __builtin_amdgcn_s_sleep(8);
      if (wall_clock64() - t0 > 2000000LL) break;   // ~20 ms watchdog
    }
  }
  __syncthreads();
  __threadfence();
}

// ---- workspace layout ----
#define SZ_ACT ((size_t)BATCH * 2048 * 2)          // one u16 activation plane
#define GSLICE ((size_t)GROWS * 2048)              // per-group slice (u16 elems)
#define OFF_A0MS ((size_t)4096)
#define OFF_A0LS (OFF_A0MS + SZ_ACT)
#define OFF_A1MS (OFF_A0LS + SZ_ACT)
#define OFF_A1LS (OFF_A1MS + SZ_ACT)
#define SZ_L1 ((size_t)BATCH * 160 * 2)
#define GSL1 ((size_t)GROWS * 160)
#define OFF_L1MS (OFF_A1LS + SZ_ACT)
#define OFF_L1LS (OFF_L1MS + SZ_L1)
#define OFF_B44 (OFF_L1LS + SZ_L1)
// weight planes (u16 elem offsets within a plane)
#define PW1   ((size_t)0)                      // [2048][160]
#define PW12  (PW1  + (size_t)2048 * 160)      // [2048][2048]
#define PW2   (PW12 + (size_t)2048 * 2048)     // [1024][2048]
#define PW22  (PW2  + (size_t)1024 * 2048)     // [1024][1024]
#define PW3   (PW22 + (size_t)1024 * 1024)     // [512][1024]
#define PW44  (PW3  + (size_t)512 * 1024)      // [128][512]
#define PWI3  (PW44 + (size_t)128 * 512)       // [128][512]
#define PLANE_ELEMS (PWI3 + (size_t)128 * 512) // 8,323,072
#define OFF_PMS (OFF_B44 + 512)
#define OFF_PLS (OFF_PMS + PLANE_ELEMS * 2)
#define WS_FULL (OFF_PLS + PLANE_ELEMS * 2)    // ~50.6 MiB
// fallback overlay (fp32 w44 / wi3p) in the plane area
#define OFF_W44F (OFF_B44 + 512)
#define OFF_WI3F (OFF_W44F + (size_t)512 * 128 * 4)
#define WS_MIN (OFF_WI3F + (size_t)512 * 128 * 4)

// One pipelined GEMM phase on this group's 128 rows: out = A @ W + bias.
// AM: 0 = A from u16 hi/lo planes (lda = plane stride), 1 = A fp32 (KrA predicate).
// BM: 0 = B from u16 planes [N][Kpad], 1 = B fp32 [K][N] row-major (KrB predicate).
// EPI: 0 = write split planes; 1 = final layer (fp32 out + carried-state planes).
template <int MI, int NI, int AM, int BM, int EPI>
__device__ void gemm_phase(int wg, uint16_t *sh,
    const uint16_t *__restrict__ Am, const uint16_t *__restrict__ Al,
    const float *__restrict__ Afp, int lda, int KrA,
    const uint16_t *__restrict__ Bm, const uint16_t *__restrict__ Bl,
    const float *__restrict__ Wfp, int ldw, int KrB,
    int Kpad, int N, const float *__restrict__ bias, int relu,
    uint16_t *__restrict__ Om, uint16_t *__restrict__ Ol, int ldo,
    float *__restrict__ fres, float *__restrict__ finit,
    uint16_t *__restrict__ hm, uint16_t *__restrict__ hl)
{
  constexpr int TM = 32 * MI, TN = 32 * NI;
  static_assert(TN == 64, "B tile fixed at 64 cols");
  const int nbs = N >> 6;
  const int active = (GROWS / TM) * nbs;
  if (wg >= active) return;
  const int mb = wg / nbs, nb = wg - mb * nbs;
  const int m_base = mb * TM, n0 = nb * TN;
  const int tid = threadIdx.x, lane = tid & 63, wid = tid >> 6;
  const int wr = wid >> 1, wc = wid & 1;
  const int r16 = lane & 15, kg = lane >> 4;

  uint16_t *sAm = sh, *sAl = sh + 10240, *sBm = sh + 20480, *sBl = sh + 25600;

  constexpr int PA = TM * 4 / NTHR;    // b128 (or 8-float) jobs per thread per plane
  V8 pam[PA], pal[PA];
  float paf[AM ? PA * 8 : 1];
  V8 pbm, pbl;
  float pbf[BM ? 8 : 1];

  f32x4 acc[MI][NI];
#pragma unroll
  for (int i = 0; i < MI; ++i)
#pragma unroll
    for (int j = 0; j < NI; ++j) acc[i][j] = {0.f, 0.f, 0.f, 0.f};

  const int NK = Kpad >> 5;

  auto PF = [&](int k0) {
    if (AM == 0) {
#pragma unroll
      for (int j = 0; j < PA; ++j) {
        const int idx = tid + j * NTHR, m = idx >> 2, ko = (idx & 3) * 8;
        const size_t o = (size_t)(m_base + m) * lda + k0 + ko;
        pam[j].q = *(const i32x4 *)(Am + o);
        pal[j].q = *(const i32x4 *)(Al + o);
      }
    } else {
#pragma unroll
      for (int j = 0; j < PA; ++j) {
        const int idx = tid + j * NTHR, m = idx >> 2, ko = (idx & 3) * 8;
        const float *sp = Afp + (size_t)(m_base + m) * lda;
#pragma unroll
        for (int t = 0; t < 8; ++t) {
          const int kk = k0 + ko + t;
          paf[j * 8 + t] = (kk < KrA) ? sp[kk] : 0.f;
        }
      }
    }
    if (BM == 0) {
      const int n = tid >> 2, ko = (tid & 3) * 8;
      const size_t o = (size_t)(n0 + n) * Kpad + k0 + ko;
      pbm.q = *(const i32x4 *)(Bm + o);
      pbl.q = *(const i32x4 *)(Bl + o);
    } else {
      const int n = tid & 63, kq = tid >> 6;
#pragma unroll
      for (int t = 0; t < 8; ++t) {
        const int kk = k0 + kq * 8 + t;
        pbf[t] = (kk < KrB) ? Wfp[(size_t)kk * ldw + n0 + n] : 0.f;
      }
    }
  };

  auto WL = [&](int buf) {
    if (AM == 0) {
#pragma unroll
      for (int j = 0; j < PA; ++j) {
        const int idx = tid + j * NTHR, m = idx >> 2, ko = (idx & 3) * 8;
        *(i32x4 *)&sAm[buf * 5120 + m * LDSTR + ko] = pam[j].q;
        *(i32x4 *)&sAl[buf * 5120 + m * LDSTR + ko] = pal[j].q;
      }
    } else {
#pragma unroll
      for (int j = 0; j < PA; ++j) {
        const int idx = tid + j * NTHR, m = idx >> 2, ko = (idx & 3) * 8;
        V8 vm, vl;
#pragma unroll
        for (int t = 0; t < 8; ++t) split_bf(paf[j * 8 + t], vm.u[t], vl.u[t]);
        *(i32x4 *)&sAm[buf * 5120 + m * LDSTR + ko] = vm.q;
        *(i32x4 *)&sAl[buf * 5120 + m * LDSTR + ko] = vl.q;
      }
    }
    if (BM == 0) {
      const int n = tid >> 2, ko = (tid & 3) * 8;
      *(i32x4 *)&sBm[buf * 2560 + n * LDSTR + ko] = pbm.q;
      *(i32x4 *)&sBl[buf * 2560 + n * LDSTR + ko] = pbl.q;
    } else {
      const int n = tid & 63, kq = tid >> 6;
      V8 vm, vl;
#pragma unroll
      for (int t = 0; t < 8; ++t) split_bf(pbf[t], vm.u[t], vl.u[t]);
      *(i32x4 *)&sBm[buf * 2560 + n * LDSTR + kq * 8] = vm.q;
      *(i32x4 *)&sBl[buf * 2560 + n * LDSTR + kq * 8] = vl.q;
    }
  };

  auto RM = [&](int buf) {
    s8b fam[MI], fal[MI], fbm[NI], fbl[NI];
#pragma unroll
    for (int i = 0; i < MI; ++i) {
      const int ro = buf * 5120 + (wr * (16 * MI) + i * 16 + r16) * LDSTR + kg * 8;
      fam[i] = *(const s8b *)&sAm[ro];
      fal[i] = *(const s8b *)&sAl[ro];
    }
#pragma unroll
    for (int j = 0; j < NI; ++j) {
      const int co = buf * 2560 + (wc * (16 * NI) + j * 16 + r16) * LDSTR + kg * 8;
      fbm[j] = *(const s8b *)&sBm[co];
      fbl[j] = *(const s8b *)&sBl[co];
    }
#pragma unroll
    for (int i = 0; i < MI; ++i)
#pragma unroll
      for (int j = 0; j < NI; ++j) {
        acc[i][j] = __builtin_amdgcn_mfma_f32_16x16x32_bf16(fam[i], fbm[j], acc[i][j], 0, 0, 0);
        acc[i][j] = __builtin_amdgcn_mfma_f32_16x16x32_bf16(fam[i], fbl[j], acc[i][j], 0, 0, 0);
        acc[i][j] = __builtin_amdgcn_mfma_f32_16x16x32_bf16(fal[i], fbm[j], acc[i][j], 0, 0, 0);
        acc[i][j] = __builtin_amdgcn_mfma_f32_16x16x32_bf16(fal[i], fbl[j], acc[i][j], 0, 0, 0);
      }
  };

  // pipeline: PF(k+1) issues under RM(k); one sync per iter
  PF(0);
  WL(0);
  int buf = 0;
  for (int k = 1;; ++k) {
    __syncthreads();
    if (k < NK) PF(k << 5);
    RM(buf);
    if (k >= NK) break;
    WL(buf ^ 1);
    buf ^= 1;
  }

  // epilogue (C/D: col = lane&15, row = (lane>>4)*4 + reg)
#pragma unroll
  for (int i = 0; i < MI; ++i)
#pragma unroll
    for (int j = 0; j < NI; ++j) {
      const int row0 = m_base + wr * (16 * MI) + i * 16 + kg * 4;
      const int col = n0 + wc * (16 * NI) + j * 16 + r16;
      if (EPI == 0) {
        const float bv = bias[col];
#pragma unroll
        for (int r = 0; r < 4; ++r) {
          float v = acc[i][j][r] + bv;
          if (relu) v = fmaxf(v, 0.f);
          uint16_t ms, ls; split_bf(v, ms, ls);
          const size_t o = (size_t)(row0 + r) * ldo + col;
          Om[o] = ms; Ol[o] = ls;
        }
      } else {
        if (col < NCLS) {
          const float bv = bias[col];
#pragma unroll
          for (int r = 0; r < 4; ++r) {
            const float v = acc[i][j][r] + bv;
            fres[(size_t)(row0 + r) * (TSEQ * NCLS) + col] = v;
            if (finit) finit[(size_t)(row0 + r) * NCLS + col] = v;
            uint16_t ms, ls; split_bf(v, ms, ls);
            const size_t ho = (size_t)(row0 + r) * 160 + 72 + col;
            hm[ho] = ms; hl[ho] = ls;
          }
        }
      }
    }
}

__device__ __forceinline__ void stage_l1_src(int wg, const float *__restrict__ src_g,
                                             uint16_t *__restrict__ l1m,
                                             uint16_t *__restrict__ l1l, int next_t) {
  if (wg < 2 || wg >= 18 || next_t >= TSEQ) return;
  const int mrow = (wg - 2) * 8;
  for (int e = threadIdx.x; e < 8 * 72; e += NTHR) {
    const int m = e / 72, c = e - (e / 72) * 72;
    const float x = src_g[(size_t)(mrow + m) * SRCROW + (size_t)(next_t - 1) * FEAT + c];
    uint16_t ms, ls; split_bf(x, ms, ls);
    const size_t o = (size_t)(mrow + m) * 160 + c;
    l1m[o] = ms; l1l[o] = ls;
  }
}

struct GPtr {
  const float *src_g, *wi1, *bi1, *wi2, *bi2, *wi25, *bi25, *bi3;
  const float *w1, *b1, *w12, *b12, *w2, *b2, *w22, *b22, *w3, *b3;
  const float *b44, *w44f, *wi3f;
  const uint16_t *pm, *pl;
  uint16_t *a0m, *a0l, *a1m, *a1l, *l1m, *l1l;
  float *out_g, *finit_g;
  unsigned *ctr;
};

template <int BMR>
__device__ void run_seq(int wg, uint16_t *sh, const GPtr &p) {
  unsigned ph = 0;
  // init MLP
  gemm_phase<4, 2, 1, 1, 0>(wg, sh, nullptr, nullptr, p.src_g, SRCROW, SRCROW,
                            nullptr, nullptr, p.wi1, 2048, SRCROW,
                            3072, 2048, p.bi1, 1, p.a0m, p.a0l, 2048,
                            nullptr, nullptr, nullptr, nullptr);
  ++ph; ctr_barrier(p.ctr, ph * WPG);
  gemm_phase<2, 2, 0, 1, 0>(wg, sh, p.a0m, p.a0l, nullptr, 2048, 0,
                            nullptr, nullptr, p.wi2, 1024, 2048,
                            2048, 1024, p.bi2, 1, p.a1m, p.a1l, 1024,
                            nullptr, nullptr, nullptr, nullptr);
  ++ph; ctr_barrier(p.ctr, ph * WPG);
  gemm_phase<2, 2, 0, 1, 0>(wg, sh, p.a1m, p.a1l, nullptr, 1024, 0,
                            nullptr, nullptr, p.wi25, 512, 1024,
                            1024, 512, p.bi25, 0, p.a0m, p.a0l, 512,
                            nullptr, nullptr, nullptr, nullptr);
  ++ph; ctr_barrier(p.ctr, ph * WPG);
  gemm_phase<2, 2, 0, BMR, 1>(wg, sh, p.a0m, p.a0l, nullptr, 512, 0,
                              p.pm + PWI3, p.pl + PWI3, p.wi3f, 128, 512,
                              512, 128, p.bi3, 0, nullptr, nullptr, 0,
                              p.out_g, p.finit_g, p.l1m, p.l1l);
  stage_l1_src(wg, p.src_g, p.l1m, p.l1l, 1);
  ++ph; ctr_barrier(p.ctr, ph * WPG);

  for (int t = 1; t < TSEQ; ++t) {
    gemm_phase<4, 2, 0, BMR, 0>(wg, sh, p.l1m, p.l1l, nullptr, 160, 0,
                                p.pm + PW1, p.pl + PW1, p.w1, 2048, 141,
                                160, 2048, p.b1, 1, p.a0m, p.a0l, 2048,
                                nullptr, nullptr, nullptr, nullptr);
    ++ph; ctr_barrier(p.ctr, ph * WPG);
    gemm_phase<4, 2, 0, BMR, 0>(wg, sh, p.a0m, p.a0l, nullptr, 2048, 0,
                                p.pm + PW12, p.pl + PW12, p.w12, 2048, 2048,
                                2048, 2048, p.b12, 1, p.a1m, p.a1l, 2048,
                                nullptr, nullptr, nullptr, nullptr);
    ++ph; ctr_barrier(p.ctr, ph * WPG);
    gemm_phase<2, 2, 0, BMR, 0>(wg, sh, p.a1m, p.a1l, nullptr, 2048, 0,
                                p.pm + PW2, p.pl + PW2, p.w2, 1024, 2048,
                                2048, 1024, p.b2, 1, p.a0m, p.a0l, 1024,
                                nullptr, nullptr, nullptr, nullptr);
    ++ph; ctr_barrier(p.ctr, ph * WPG);
    gemm_phase<2, 2, 0, BMR, 0>(wg, sh, p.a0m, p.a0l, nullptr, 1024, 0,
                                p.pm + PW22, p.pl + PW22, p.w22, 1024, 1024,
                                1024, 1024, p.b22, 1, p.a1m, p.a1l, 1024,
                                nullptr, nullptr, nullptr, nullptr);
    ++ph; ctr_barrier(p.ctr, ph * WPG);
    gemm_phase<2, 2, 0, BMR, 0>(wg, sh, p.a1m, p.a1l, nullptr, 1024, 0,
                                p.pm + PW3, p.pl + PW3, p.w3, 512, 1024,
                                1024, 512, p.b3, 1, p.a0m, p.a0l, 512,
                                nullptr, nullptr, nullptr, nullptr);
    ++ph; ctr_barrier(p.ctr, ph * WPG);
    gemm_phase<2, 2, 0, BMR, 1>(wg, sh, p.a0m, p.a0l, nullptr, 512, 0,
                                p.pm + PW44, p.pl + PW44, p.w44f, 128, 512,
                                512, 128, p.b44, 0, nullptr, nullptr, 0,
                                p.out_g + (size_t)t * NCLS, nullptr, p.l1m, p.l1l);
    stage_l1_src(wg, p.src_g, p.l1m, p.l1l, t + 1);
    ++ph; ctr_barrier(p.ctr, ph * WPG);
  }
}

extern "C" __global__ void __launch_bounds__(NTHR, 1)
sbfc_kernel(const float *__restrict__ src,
            const float *__restrict__ wi1, const float *__restrict__ bi1,
            const float *__restrict__ wi2, const float *__restrict__ bi2,
            const float *__restrict__ wi25, const float *__restrict__ bi25,
            const float *__restrict__ wi3, const float *__restrict__ bi3,
            const float *__restrict__ w1, const float *__restrict__ b1,
            const float *__restrict__ w12, const float *__restrict__ b12,
            const float *__restrict__ w2, const float *__restrict__ b2,
            const float *__restrict__ w22, const float *__restrict__ b22,
            const float *__restrict__ w3, const float *__restrict__ b3,
            const float *__restrict__ w4, const float *__restrict__ b4,
            const float *__restrict__ w4d, const float *__restrict__ b4d,
            float *__restrict__ out, char *ws, int ps)
{
  __shared__ uint16_t sh[30720];   // 61,440 B: dbuf A(2x128x40x2pl) + B(2x64x40x2pl)

  const int bid = blockIdx.x;
  const int g = bid & (NG - 1);
  const int wg = bid >> 3;
  const int tid = threadIdx.x;

  uint16_t *pm = (uint16_t *)(ws + OFF_PMS);
  uint16_t *pl = (uint16_t *)(ws + OFF_PLS);
  float *b44 = (float *)(ws + OFF_B44);
  float *w44f = (float *)(ws + OFF_W44F);
  float *wi3f = (float *)(ws + OFF_WI3F);

  // ---- prep ----
  if (ps) {
    if (bid < 16) {                       // fused w4@w4d -> planes [128][512]
      const int kb = bid * 32;
      for (int e = tid; e < 32 * 128; e += NTHR) {
        const int k = kb + (e >> 7), n = e & 127;
        float s = 0.f;
        if (n < NCLS) {
          const float *w4r = w4 + (size_t)k * 512;
          for (int j = 0; j < 512; ++j) s = fmaf(w4r[j], w4d[(size_t)j * NCLS + n], s);
        }
        uint16_t ms, ls; split_bf(s, ms, ls);
        pm[PW44 + (size_t)n * 512 + k] = ms;
        pl[PW44 + (size_t)n * 512 + k] = ls;
      }
    } else if (bid < 24) {                // wi3 padded -> planes [128][512]
      const int kb = (bid - 16) * 64;
      for (int e = tid; e < 64 * 128; e += NTHR) {
        const int k = kb + (e >> 7), n = e & 127;
        const float x = (n < NCLS) ? wi3[(size_t)k * NCLS + n] : 0.f;
        uint16_t ms, ls; split_bf(x, ms, ls);
        pm[PWI3 + (size_t)n * 512 + k] = ms;
        pl[PWI3 + (size_t)n * 512 + k] = ls;
      }
    } else if (bid == 24) {               // b44 = b4 @ w4d + b4d
      for (int n = tid; n < 128; n += NTHR) {
        float s = 0.f;
        if (n < NCLS) {
          s = b4d[n];
          for (int j = 0; j < 512; ++j) s = fmaf(b4[j], w4d[(size_t)j * NCLS + n], s);
        }
        b44[n] = s;
      }
    } else if (bid < 29) {                // zero l1 pad cols 141..159
      uint16_t *l1m0 = (uint16_t *)(ws + OFF_L1MS);
      uint16_t *l1l0 = (uint16_t *)(ws + OFF_L1LS);
      const int part = bid - 25;
      for (int e = tid; e < 256 * 19; e += NTHR) {
        const int m = part * 256 + e / 19, c = 141 + (e - (e / 19) * 19);
        const size_t o = (size_t)(m >> 7) * GSL1 + (size_t)(m & 127) * 160 + c;
        l1m0[o] = 0; l1l0[o] = 0;
      }
    } else if (bid < 157) {               // big-matrix split: 32768 column-chunk jobs
      const int jid = (bid - 29) * NTHR + tid;
      if (jid < 32768) {
        int base, Nn, Kp, Kr; const float *sw; size_t doff;
        if (jid < 2048)       { base = 0;     Nn = 2048; Kp = 160;  Kr = 141;  sw = w1;  doff = PW1; }
        else if (jid < 18432) { base = 2048;  Nn = 2048; Kp = 2048; Kr = 2048; sw = w12; doff = PW12; }
        else if (jid < 26624) { base = 18432; Nn = 1024; Kp = 2048; Kr = 2048; sw = w2;  doff = PW2; }
        else if (jid < 30720) { base = 26624; Nn = 1024; Kp = 1024; Kr = 1024; sw = w22; doff = PW22; }
        else                  { base = 30720; Nn = 512;  Kp = 1024; Kr = 1024; sw = w3;  doff = PW3; }
        const int local = jid - base, n = local % Nn, c = local / Nn;
        const int k0 = c * 256, k1 = (k0 + 256 < Kp) ? k0 + 256 : Kp;
        uint16_t *dm = pm + doff + (size_t)n * Kp;
        uint16_t *dl = pl + doff + (size_t)n * Kp;
        for (int k = k0; k < k1; k += 8) {
          V8 vm, vl;
#pragma unroll
          for (int t = 0; t < 8; ++t) {
            const int kk = k + t;
            const float x = (kk < Kr) ? sw[(size_t)kk * Nn + n] : 0.f;
            split_bf(x, vm.u[t], vl.u[t]);
          }
          *(i32x4 *)&dm[k] = vm.q;
          *(i32x4 *)&dl[k] = vl.q;
        }
      }
    }
  } else {
    // fallback prep: fp32 w44 [512][128], fp32 wi3p [512][128], b44, l1 pad
    if (bid < 16) {
      const int kb = bid * 32;
      for (int e = tid; e < 32 * 128; e += NTHR) {
        const int k = kb + (e >> 7), n = e & 127;
        float s = 0.f;
        if (n < NCLS) {
          const float *w4r = w4 + (size_t)k * 512;
          for (int j = 0; j < 512; ++j) s = fmaf(w4r[j], w4d[(size_t)j * NCLS + n], s);
        }
        w44f[(size_t)k * 128 + n] = s;
      }
    } else if (bid < 24) {
      const int kb = (bid - 16) * 64;
      for (int e = tid; e < 64 * 128; e += NTHR) {
        const int k = kb + (e >> 7), n = e & 127;
        wi3f[(size_t)k * 128 + n] = (n < NCLS) ? wi3[(size_t)k * NCLS + n] : 0.f;
      }
    } else if (bid == 24) {
      for (int n = tid; n < 128; n += NTHR) {
        float s = 0.f;
        if (n < NCLS) {
          s = b4d[n];
          for (int j = 0; j < 512; ++j) s = fmaf(b4[j], w4d[(size_t)j * NCLS + n], s);
        }
        b44[n] = s;
      }
    } else if (bid < 29) {
      uint16_t *l1m0 = (uint16_t *)(ws + OFF_L1MS);
      uint16_t *l1l0 = (uint16_t *)(ws + OFF_L1LS);
      const int part = bid - 25;
      for (int e = tid; e < 256 * 19; e += NTHR) {
        const int m = part * 256 + e / 19, c = 141 + (e - (e / 19) * 19);
        const size_t o = (size_t)(m >> 7) * GSL1 + (size_t)(m & 127) * 160 + c;
        l1m0[o] = 0; l1l0[o] = 0;
      }
    }
  }
  ctr_barrier((unsigned *)(ws + 2048), 256);   // publish prep

  GPtr p;
  p.src_g = src + (size_t)g * GROWS * SRCROW;
  p.wi1 = wi1; p.bi1 = bi1; p.wi2 = wi2; p.bi2 = bi2;
  p.wi25 = wi25; p.bi25 = bi25; p.bi3 = bi3;
  p.w1 = w1; p.b1 = b1; p.w12 = w12; p.b12 = b12;
  p.w2 = w2; p.b2 = b2; p.w22 = w22; p.b22 = b22; p.w3 = w3; p.b3 = b3;
  p.b44 = b44; p.w44f = w44f; p.wi3f = wi3f;
  p.pm = pm; p.pl = pl;
  p.a0m = (uint16_t *)(ws + OFF_A0MS) + g * GSLICE;
  p.a0l = (uint16_t *)(ws + OFF_A0LS) + g * GSLICE;
  p.a1m = (uint16_t *)(ws + OFF_A1MS) + g * GSLICE;
  p.a1l = (uint16_t *)(ws + OFF_A1LS) + g * GSLICE;
  p.l1m = (uint16_t *)(ws + OFF_L1MS) + g * GSL1;
  p.l1l = (uint16_t *)(ws + OFF_L1LS) + g * GSL1;
  p.out_g = out + (size_t)g * GROWS * TSEQ * NCLS;
  p.finit_g = out + (size_t)BATCH * TSEQ * NCLS + (size_t)g * GROWS * NCLS;
  p.ctr = (unsigned *)ws + g * 16;

  if (ps) run_seq<0>(wg, sh, p);
  else    run_seq<1>(wg, sh, p);
}

extern "C" void kernel_launch(void *const *d_in, const int *in_sizes, int n_in,
                              void *d_out, int out_size, void *d_ws, size_t ws_size,
                              hipStream_t stream) {
  if (ws_size < WS_MIN) return;   // clean mismatch beats an OOB crash

  const float *src = (const float *)d_in[0];
  const float *wi1 = (const float *)d_in[1];
  const float *bi1 = (const float *)d_in[2];
  const float *wi2 = (const float *)d_in[3];
  const float *bi2 = (const float *)d_in[4];
  const float *wi25 = (const float *)d_in[5];
  const float *bi25 = (const float *)d_in[6];
  const float *wi3 = (const float *)d_in[7];
  const float *bi3 = (const float *)d_in[8];
  const float *w1 = (const float *)d_in[9];
  const float *b1 = (const float *)d_in[10];
  const float *w12 = (const float *)d_in[11];
  const float *b12 = (const float *)d_in[12];
  const float *w2 = (const float *)d_in[13];
  const float *b2 = (const float *)d_in[14];
  const float *w22 = (const float *)d_in[15];
  const float *b22 = (const float *)d_in[16];
  const float *w3 = (const float *)d_in[17];
  const float *b3 = (const float *)d_in[18];
  const float *w4 = (const float *)d_in[19];
  const float *b4 = (const float *)d_in[20];
  const float *w4d = (const float *)d_in[21];
  const float *b4d = (const float *)d_in[22];
  float *out = (float *)d_out;
  char *ws = (char *)d_ws;
  int ps = (ws_size >= WS_FULL) ? 1 : 0;

  hipMemsetAsync(d_ws, 0, 4096, stream);   // barrier counters

  void *args[] = {&src, &wi1, &bi1, &wi2, &bi2, &wi25, &bi25, &wi3, &bi3,
                  &w1, &b1, &w12, &b12, &w2, &b2, &w22, &b22, &w3, &b3,
                  &w4, &b4, &w4d, &b4d, &out, &ws, &ps};

  int coop = 0;
  hipDeviceGetAttribute(&coop, hipDeviceAttributeCooperativeLaunch, 0);
  hipError_t rc = hipErrorUnknown;
  if (coop) {
    rc = hipLaunchCooperativeKernel((const void *)sbfc_kernel, dim3(NG * WPG),
                                    dim3(NTHR), args, 0, stream);
  }
  if (rc != hipSuccess) {
    hipLaunchKernelGGL(sbfc_kernel, dim3(NG * WPG), dim3(NTHR), 0, stream,
                       src, wi1, bi1, wi2, bi2, wi25, bi25, wi3, bi3,
                       w1, b1, w12, b12, w2, b2, w22, b22, w3, b3, w4, b4, w4d, b4d,
                       out, ws, ps);
  }
}